// Round 10
// baseline (342.039 us; speedup 1.0000x reference)
//
#include <hip/hip_runtime.h>
#include <hip/hip_fp8.h>
#include <stdint.h>

// Problem constants (fixed by reference setup_inputs)
constexpr int N    = 8192;
constexpr int D    = 512;
constexpr int KEXT = 8;
constexpr int NCLS = 1000;
#define TAU_INV  14.285714285714285714f   // 1/0.07
#define SQRT_TI  3.7796447300922722f      // sqrt(1/0.07); folded into packed fp8

typedef long   long2_t __attribute__((ext_vector_type(2)));  // 16B = 2 fp8 MFMA operands
typedef float  f32x4   __attribute__((ext_vector_type(4)));

typedef __attribute__((address_space(1))) void gvoid;
typedef __attribute__((address_space(3))) void lvoid;

__device__ __forceinline__ uint32_t pack4_e4m3(float a, float b, float c, float d) {
    __hip_fp8_e4m3 A(a), B(b), C(c), D(d);   // OCP e4m3fn on gfx950
    return (uint32_t)A.__x | ((uint32_t)B.__x << 8) |
           ((uint32_t)C.__x << 16) | ((uint32_t)D.__x << 24);
}
__device__ __forceinline__ float f8tof(uint32_t b) {
    __hip_fp8_e4m3 v; v.__x = (uint8_t)b; return (float)v;
}

// ---------------- fused prep: histogram + fp8 fragment-packing of q --------
// qf8 layout (validated R7-R9, absmax 0.0): 16B granule slot = (t*512 +
// ks2*64 + quad*16 + l15), t=16-row tile, ks2=64-wide K-macrostep. Bytes
// [0..8) hold q[t*16+l15][ks2*64+quad*8 ..+8)*SQRT_TI, bytes [8..16) the +32
// window. Band ib (8 tiles) is a CONTIGUOUS 64KB region -> linear LDS DMA.
__global__ void prep_k(const float* __restrict__ q, const int* __restrict__ y,
                       uint32_t* __restrict__ qf8, int* __restrict__ counts,
                       float* __restrict__ invy, float* __restrict__ neg,
                       float* __restrict__ out) {
    const int b = blockIdx.x, tid = threadIdx.x;
    if (b == 0) {
        __shared__ int h[NCLS];
        for (int i = tid; i < NCLS; i += 256) h[i] = 0;
        __syncthreads();
        for (int i = tid; i < N; i += 256) atomicAdd(&h[y[i]], 1);
        __syncthreads();
        for (int i = tid; i < NCLS; i += 256) counts[i] = h[i];
        if (tid == 0) out[0] = 0.f;
        for (int i = tid; i < N; i += 256) invy[i] = 1.0f / (float)h[y[i]];
        return;
    }
    const int gid = (b - 1) * 256 + tid;     // over N*32 granules
    const int row = gid >> 5;                // source row of q
    const int c   = gid & 31;                // granule within row
    const int ks2 = c >> 2, quad = c & 3;
    const float* src = q + (size_t)row * D + ks2 * 64 + quad * 8;
    float4 v0 = *reinterpret_cast<const float4*>(src);
    float4 v1 = *reinterpret_cast<const float4*>(src + 4);
    float4 v2 = *reinterpret_cast<const float4*>(src + 32);
    float4 v3 = *reinterpret_cast<const float4*>(src + 36);
    uint4 o;
    o.x = pack4_e4m3(v0.x * SQRT_TI, v0.y * SQRT_TI, v0.z * SQRT_TI, v0.w * SQRT_TI);
    o.y = pack4_e4m3(v1.x * SQRT_TI, v1.y * SQRT_TI, v1.z * SQRT_TI, v1.w * SQRT_TI);
    o.z = pack4_e4m3(v2.x * SQRT_TI, v2.y * SQRT_TI, v2.z * SQRT_TI, v2.w * SQRT_TI);
    o.w = pack4_e4m3(v3.x * SQRT_TI, v3.y * SQRT_TI, v3.z * SQRT_TI, v3.w * SQRT_TI);
    const int t = row >> 4, l15 = row & 15;
    reinterpret_cast<uint4*>(qf8)[(size_t)t * 512 + ks2 * 64 + quad * 16 + l15] = o;
    if (gid < N) neg[gid] = 0.f;
}

// ---------------- band-sweep GEMM (q @ q^T) + MASKLESS epilogue ------------
// ns_all[i] = sum_{j != i} exp(a_ij) * invy[j] over ALL columns — no label
// logic in the hot loop (same-class + k_sims handled sparsely in finalize).
// Per element: exp + diag-cmp/sel + fma (~5 VALU, was ~10 with masks).
// B prefetch: 3-slot, distance-2 (AITER-style fine-grained vmcnt); A from
// LDS with distance-1 double buffer.
__global__ __launch_bounds__(256, 2) void gemm_k(
        const uint32_t* __restrict__ qf8,
        const float* __restrict__ invy,
        float* __restrict__ neg_sum) {
    __shared__ long2_t Asl[4096];       // 64KB: band's 8 tiles x 512 granules
    __shared__ float redN[2][128];

    const int tid  = threadIdx.x;
    const int wave = tid >> 6;
    const int lane = tid & 63;
    const int quad = lane >> 4;
    const int l15  = lane & 15;

    const int ib     = blockIdx.x >> 3;       // row band 0..63
    const int jchunk = blockIdx.x & 7;        // 1024-col chunk
    const int ibase  = ib * 128;

    // ---- DMA A-band into LDS: pure linear 64KB copy ----
    {
        const uint32_t* src = qf8 + (size_t)ib * 16384;   // 4096 granules
#pragma unroll
        for (int it = 0; it < 16; it++) {
            const int idx = it * 256 + tid;
            __builtin_amdgcn_global_load_lds((gvoid*)(src + idx * 4),
                                             (lvoid*)(Asl + idx), 16, 0, 0);
        }
    }
    __syncthreads();   // DMA drained (compiler emits vmcnt(0) before barrier)

    // wave position: 2x2 waves over each 128x128 subtile
    const int wr = (wave >> 1) * 64;
    const int wc = (wave & 1) * 64;
    const int half = wave & 1;

    float negp[16];
#pragma unroll
    for (int e = 0; e < 16; e++) negp[e] = 0.f;

    const long2_t* fb = reinterpret_cast<const long2_t*>(qf8);
    const long2_t* pB[4];
#pragma unroll
    for (int m = 0; m < 4; m++)
        pB[m] = fb + (size_t)(jchunk * 64 + (wc >> 4) + m) * 512 + lane;

    // single LDS base for A: imm offsets m*512 + ks2*64 granules
    const long2_t* As = Asl + (wr >> 4) * 512 + lane;

    for (int jt = 0; jt < 8; jt++) {
        const int j0 = jchunk * 1024 + jt * 128;

        int   jc[4];
        float icj[4];
#pragma unroll
        for (int mj = 0; mj < 4; mj++) {
            jc[mj]  = j0 + wc + mj * 16 + l15;
            icj[mj] = invy[jc[mj]];
        }

        f32x4 acc[4][4];
#pragma unroll
        for (int a = 0; a < 4; a++)
#pragma unroll
            for (int c = 0; c < 4; c++) acc[a][c] = (f32x4)0.0f;

        // ---- K-loop: B 3-slot distance-2 prefetch, A LDS distance-1 ----
        long2_t bf[3][4], af[2][4];
#pragma unroll
        for (int m = 0; m < 4; m++) {
            bf[0][m] = pB[m][0];
            bf[1][m] = pB[m][64];
            af[0][m] = As[m * 512];
        }
#pragma unroll
        for (int ks2 = 0; ks2 < 8; ks2++) {
            const int cur = ks2 % 3;
            if (ks2 + 2 < 8) {
                const int ns = (ks2 + 2) % 3;
#pragma unroll
                for (int m = 0; m < 4; m++) bf[ns][m] = pB[m][(ks2 + 2) * 64];
            }
            const int ac = ks2 & 1;
            if (ks2 < 7) {
#pragma unroll
                for (int m = 0; m < 4; m++) af[ac ^ 1][m] = As[m * 512 + (ks2 + 1) * 64];
            }
#pragma unroll
            for (int mi = 0; mi < 4; mi++)
#pragma unroll
                for (int mj = 0; mj < 4; mj++)
                    acc[mi][mj] = __builtin_amdgcn_mfma_f32_16x16x32_fp8_fp8(
                        af[ac][mi].x, bf[cur][mj].x, acc[mi][mj], 0, 0, 0);
#pragma unroll
            for (int mi = 0; mi < 4; mi++)
#pragma unroll
                for (int mj = 0; mj < 4; mj++)
                    acc[mi][mj] = __builtin_amdgcn_mfma_f32_16x16x32_fp8_fp8(
                        af[ac][mi].y, bf[cur][mj].y, acc[mi][mj], 0, 0, 0);
        }
#pragma unroll
        for (int m = 0; m < 4; m++) pB[m] += 4096;   // next 128 cols (8 tiles)

        // ---- maskless epilogue: ns += exp(a)*icj, diagonal excluded ----
#pragma unroll
        for (int mi = 0; mi < 4; mi++) {
#pragma unroll
            for (int r = 0; r < 4; r++) {
                const int irow = ibase + wr + mi * 16 + quad * 4 + r; // C/D row
                float ns = 0.f;
#pragma unroll
                for (int mj = 0; mj < 4; mj++) {
                    float ex = __expf(acc[mi][mj][r]);
                    ex = (irow == jc[mj]) ? 0.f : ex;    // exact diag exclusion
                    ns = fmaf(ex, icj[mj], ns);
                }
                negp[mi * 4 + r] += ns;
            }
        }
    }

    // ---- commit: 16-lane reduce -> LDS column-half combine -> 128 atomics ----
#pragma unroll
    for (int mi = 0; mi < 4; mi++) {
#pragma unroll
        for (int r = 0; r < 4; r++) {
            float ns = negp[mi * 4 + r];
#pragma unroll
            for (int off = 1; off < 16; off <<= 1) ns += __shfl_xor(ns, off);
            if (l15 == 0) redN[half][wr + mi * 16 + quad * 4 + r] = ns;
        }
    }
    __syncthreads();
    if (tid < 128)
        atomicAdd(&neg_sum[ibase + tid], redN[0][tid] + redN[1][tid]);
}

// ---------------- finalize: k_sims + sparse same-class pass + loss ----------
// One wave per row: (a) k_sims in fp32; (b) ballot-scan y for same-class js;
// per hit: pos += exp(fp32 dot/tau)  [higher accuracy than the fp8 GEMM] and
// corr += exp(fp8 dot)  [recomputes the GEMM's term to subtract from ns_all].
__global__ void finalize_k(const float* __restrict__ q, const float* __restrict__ kmat,
                           const int* __restrict__ y, const int* __restrict__ counts,
                           const float* __restrict__ neg_sum,
                           const uint32_t* __restrict__ qf8,
                           float* __restrict__ out) {
    __shared__ float part[4];
    const int wave = threadIdx.x >> 6, lane = threadIdx.x & 63;
    const int i = blockIdx.x * 4 + wave;

    const float4* q4 = reinterpret_cast<const float4*>(q);
    float4 qa = q4[(size_t)i * 128 + lane], qb = q4[(size_t)i * 128 + 64 + lane];

    // ---- k_sims (external positives), fp32 ----
    const float4* k4 = reinterpret_cast<const float4*>(kmat) + (size_t)i * KEXT * 128;
    float esum = 0.f;
    for (int kk = 0; kk < KEXT; kk++) {
        float4 ka = k4[(size_t)kk * 128 + lane];
        float4 kb = k4[(size_t)kk * 128 + 64 + lane];
        float p = qa.x * ka.x;
        p = fmaf(qa.y, ka.y, p); p = fmaf(qa.z, ka.z, p); p = fmaf(qa.w, ka.w, p);
        p = fmaf(qb.x, kb.x, p); p = fmaf(qb.y, kb.y, p);
        p = fmaf(qb.z, kb.z, p); p = fmaf(qb.w, kb.w, p);
#pragma unroll
        for (int off = 1; off < 64; off <<= 1) p += __shfl_xor(p, off);
        esum += __expf(p * TAU_INV);
    }

    // ---- fp8 row-i fragment cache (lanes 0..31 hold one 16B granule) ----
    const uint4* f4 = reinterpret_cast<const uint4*>(qf8);
    const bool act = lane < 32;
    const int ks2 = lane >> 2, quad = lane & 3;
    const size_t goff = (size_t)ks2 * 64 + quad * 16;
    uint4 iv = act ? f4[(size_t)(i >> 4) * 512 + goff + (i & 15)] : uint4{0, 0, 0, 0};
    float fi[16];
#pragma unroll
    for (int w = 0; w < 4; w++) {
        uint32_t word = (&iv.x)[w];
#pragma unroll
        for (int t = 0; t < 4; t++) fi[w * 4 + t] = f8tof((word >> (8 * t)) & 0xffu);
    }

    const int myy = y[i];
    float pos = 0.f, corr = 0.f;
    for (int it = 0; it < 128; it++) {
        unsigned long long m = __ballot(y[it * 64 + lane] == myy);
        if (it == (i >> 6)) m &= ~(1ull << (i & 63));
        while (m) {
            const int b = __builtin_ctzll(m); m &= m - 1;
            const int j = it * 64 + b;
            // fp32 dot (pos)
            float4 ja = q4[(size_t)j * 128 + lane], jb = q4[(size_t)j * 128 + 64 + lane];
            float p = qa.x * ja.x;
            p = fmaf(qa.y, ja.y, p); p = fmaf(qa.z, ja.z, p); p = fmaf(qa.w, ja.w, p);
            p = fmaf(qb.x, jb.x, p); p = fmaf(qb.y, jb.y, p);
            p = fmaf(qb.z, jb.z, p); p = fmaf(qb.w, jb.w, p);
            // fp8 dot (corr) — same quantized values the GEMM consumed
            uint4 jv = act ? f4[(size_t)(j >> 4) * 512 + goff + (j & 15)] : uint4{0, 0, 0, 0};
            float p8 = 0.f;
#pragma unroll
            for (int w = 0; w < 4; w++) {
                uint32_t word = (&jv.x)[w];
#pragma unroll
                for (int t = 0; t < 4; t++)
                    p8 = fmaf(fi[w * 4 + t], f8tof((word >> (8 * t)) & 0xffu), p8);
            }
#pragma unroll
            for (int off = 1; off < 64; off <<= 1) {
                p  += __shfl_xor(p, off);
                p8 += __shfl_xor(p8, off);
            }
            pos  += __expf(p * TAU_INV);
            corr += __expf(p8);
        }
    }

    if (lane == 0) {
        const float ici = 1.0f / (float)counts[myy];
        float den_sum = neg_sum[i] - corr * ici;
        float num = logf(esum + pos);
        float den = logf(den_sum);
        float cnt = (float)(counts[myy] - 1 + KEXT);  // same_class_counts, label-only
        part[wave] = -(num - den) / (cnt * (float)N);
    }
    __syncthreads();
    if (threadIdx.x == 0)
        atomicAdd(out, part[0] + part[1] + part[2] + part[3]);
}

// ---------------- launch ----------------
extern "C" void kernel_launch(void* const* d_in, const int* in_sizes, int n_in,
                              void* d_out, int out_size, void* d_ws, size_t ws_size,
                              hipStream_t stream) {
    const float* q    = (const float*)d_in[0];
    const float* kmat = (const float*)d_in[1];
    const int*   y    = (const int*)d_in[2];
    float* out = (float*)d_out;

    char* ws = (char*)d_ws;
    uint32_t* qf8  = (uint32_t*)ws;                 // 4 MB: packed fp8 fragments
    int*   counts  = (int*)  (ws + 4194304);        // 1000 ints
    float* invy    = (float*)(ws + 4198400);        // N floats: 1/count[y[j]]
    float* neg     = (float*)(ws + 4231168);        // N floats

    prep_k    <<<1 + (N * 32) / 256, 256, 0, stream>>>(q, y, qf8, counts, invy, neg, out);
    gemm_k    <<<512, 256, 0, stream>>>(qf8, invy, neg);
    finalize_k<<<N / 4, 256, 0, stream>>>(q, kmat, y, counts, neg, qf8, out);
}